// Round 10
// baseline (230.447 us; speedup 1.0000x reference)
//
#include <hip/hip_runtime.h>
#include <hip/hip_bf16.h>

#define NNODE 100000
#define NEDGE 1600000
#define NBLK_SCAN 98     // ceil(100000/1024)
#define KPH_BLOCKS 1564  // covers 100096 nodes (64/block) and 400384 int4 edges
#define FLAGBIT 0x80000000u

static __device__ __forceinline__ uint32_t pack_bf16(float a, float b) {
    __hip_bfloat162 t = __float22bfloat162_rn(make_float2(a, b));
    return *(uint32_t*)&t;
}

// ---------------- K1: hist atomics + register-only proj fused per block ----------------
__global__ __launch_bounds__(256) void k_proj_hist(
        const float* __restrict__ hin, const float* __restrict__ Wfc,
        const float* __restrict__ attn_l, const float* __restrict__ attn_r,
        uint32_t* __restrict__ feat, float* __restrict__ el, float* __restrict__ er,
        const int* __restrict__ dst, int* __restrict__ cnt, int* __restrict__ pos) {
    int tid = threadIdx.x;
    // ---- hist: one int4 per thread, atomics issued first ----
    int ei = blockIdx.x * 256 + tid;
    bool have = ei < NEDGE / 4;
    int4 d, p;
    if (have) {
        d = ((const int4*)dst)[ei];
        p.x = atomicAdd(&cnt[d.x], 1);
        p.y = atomicAdd(&cnt[d.y], 1);
        p.z = atomicAdd(&cnt[d.z], 1);
        p.w = atomicAdd(&cnt[d.w], 1);
    }
    // ---- proj: 16 nodes per wave, lane owns 2 cols, W pair in regs ----
    int l = tid & 63;
    int w = tid >> 6;
    int nbase = blockIdx.x * 64 + w * 16;
    int c0 = l * 2;
    float2 wreg[32];
#pragma unroll
    for (int k = 0; k < 32; k++)
        wreg[k] = *(const float2*)&Wfc[k * 128 + c0];
    float al0 = attn_l[c0], al1 = attn_l[c0 + 1];
    float ar0 = attn_r[c0], ar1 = attn_r[c0 + 1];
#pragma unroll 4
    for (int i = 0; i < 16; i++) {
        int n = nbase + i;
        if (n >= NNODE) break;           // wave-uniform
        float4 hv[8];
#pragma unroll
        for (int j = 0; j < 8; j++)
            hv[j] = *(const float4*)&hin[n * 32 + j * 4];   // broadcast load
        float a0 = 0.f, a1 = 0.f;
#pragma unroll
        for (int j = 0; j < 8; j++) {
            a0 = fmaf(hv[j].x, wreg[j * 4 + 0].x, a0); a1 = fmaf(hv[j].x, wreg[j * 4 + 0].y, a1);
            a0 = fmaf(hv[j].y, wreg[j * 4 + 1].x, a0); a1 = fmaf(hv[j].y, wreg[j * 4 + 1].y, a1);
            a0 = fmaf(hv[j].z, wreg[j * 4 + 2].x, a0); a1 = fmaf(hv[j].z, wreg[j * 4 + 2].y, a1);
            a0 = fmaf(hv[j].w, wreg[j * 4 + 3].x, a0); a1 = fmaf(hv[j].w, wreg[j * 4 + 3].y, a1);
        }
        float ep = a0 * al0 + a1 * al1;
        float rp = a0 * ar0 + a1 * ar1;
#pragma unroll
        for (int m = 8; m; m >>= 1) {
            ep += __shfl_xor(ep, m);
            rp += __shfl_xor(rp, m);
        }
        if ((l & 15) == 0) {
            el[n * 4 + (l >> 4)] = ep;
            er[n * 4 + (l >> 4)] = rp;
        }
        feat[(size_t)n * 64 + l] = pack_bf16(a0, a1);       // coalesced u32
    }
    // ---- pos write: waits on atomic returns (hidden behind proj) ----
    if (have) ((int4*)pos)[ei] = p;
}

// ---------------- single-kernel exclusive scan over cnt -> offa ----------------
__global__ __launch_bounds__(256) void k_scan(
        const int* __restrict__ cnt, unsigned* __restrict__ word,
        int* __restrict__ offa) {
    __shared__ int s[256];
    __shared__ int sBase;
    int t = threadIdx.x;
    int b = blockIdx.x;
    int base = b * 1024 + t * 4;
    int v[4];
#pragma unroll
    for (int i = 0; i < 4; i++) {
        int n = base + i;
        v[i] = (n < NNODE) ? cnt[n] : 0;
    }
    int sum = v[0] + v[1] + v[2] + v[3];
    s[t] = sum;
    __syncthreads();
    for (int d = 1; d < 256; d <<= 1) {
        int x = (t >= d) ? s[t - d] : 0;
        __syncthreads();
        s[t] += x;
        __syncthreads();
    }
    int excl = s[t] - sum;
    if (t == 255)
        __hip_atomic_store(&word[b], (unsigned)s[255] | FLAGBIT,
                           __ATOMIC_RELEASE, __HIP_MEMORY_SCOPE_AGENT);
    if (t < 64) {
        unsigned acc = 0;
        for (int i = t; i < b; i += 64) {
            unsigned wv;
            do {
                wv = __hip_atomic_load(&word[i], __ATOMIC_ACQUIRE, __HIP_MEMORY_SCOPE_AGENT);
            } while (!(wv & FLAGBIT));
            acc += wv & ~FLAGBIT;
        }
#pragma unroll
        for (int o = 32; o; o >>= 1) acc += __shfl_down(acc, o);
        if (t == 0) sBase = (int)acc;
    }
    __syncthreads();
    int o0 = sBase + excl;
#pragma unroll
    for (int i = 0; i < 4; i++) {
        int n = base + i;
        if (n < NNODE) { offa[n] = o0; o0 += v[i]; }
    }
    if (b == NBLK_SCAN - 1 && t == 255) offa[NNODE] = NEDGE;
}

// ---------------- scatter: atomic-free, pos precomputed ----------------
__global__ __launch_bounds__(256) void k_scatter(const int* __restrict__ src,
                                                 const int* __restrict__ dst,
                                                 const int* __restrict__ pos,
                                                 const int* __restrict__ offa,
                                                 int* __restrict__ ssrc) {
    int i = blockIdx.x * 256 + threadIdx.x;
    if (i >= NEDGE / 4) return;
    int4 s = ((const int4*)src)[i];
    int4 d = ((const int4*)dst)[i];
    int4 p = ((const int4*)pos)[i];
    int o0 = offa[d.x];
    int o1 = offa[d.y];
    int o2 = offa[d.z];
    int o3 = offa[d.w];
    ssrc[o0 + p.x] = s.x;
    ssrc[o1 + p.y] = s.y;
    ssrc[o2 + p.z] = s.z;
    ssrc[o3 + p.w] = s.w;
}

// ---------------- K2': wave-per-node gather, 16-deep MLP, 2 node-groups/block ----
#define NPB 4
#define NGROUP 2
union SmemU {
    struct { int sS[NPB][64]; float sE[NPB][64][4]; } g;      // gather phase
    struct { float sv[NPB][128]; float sacc[NPB][2][32]; } e; // epilogue phase
};

__global__ __launch_bounds__(256) void k_gather(
        const int* __restrict__ off, const int* __restrict__ ssrc,
        const float* __restrict__ el, const float* __restrict__ er,
        const uint32_t* __restrict__ feat, const float* __restrict__ bias_gat,
        const float* __restrict__ Wout, const float* __restrict__ b_out,
        const float* __restrict__ hin, float* __restrict__ out) {
    __shared__ float sW[128 * 32];              // 16 KB (loaded once, used NGROUP times)
    __shared__ __align__(16) SmemU U;           // 5 KB
    int tid = threadIdx.x;
    for (int i = tid * 4; i < 4096; i += 1024)
        *(float4*)&sW[i] = *(const float4*)&Wout[i];
    int w = tid >> 6;
    int l = tid & 63;
    int c0 = l * 2;
    int hh = l >> 4;
    int j = tid & 31, g2 = (l >> 5);

    for (int ng = 0; ng < NGROUP; ng++) {
        int n = (blockIdx.x * NGROUP + ng) * NPB + w;   // grid exact: 12500*2*4 = 100000
        float2 acc = make_float2(0.f, 0.f);
        float den = 0.f;
        int beg = off[n], end = off[n + 1];
        float4 erv = *(const float4*)&er[n * 4];

        for (int base = beg; base < end; base += 64) {
            int cnt = end - base; if (cnt > 64) cnt = 64;
            // phase A: parallel metadata load; pad slots reuse lane0's src, weight 0
            int s = 0;
            float4 e4 = make_float4(0.f, 0.f, 0.f, 0.f);
            if (l < cnt) {
                s = ssrc[base + l];
                float4 ev = *(const float4*)&el[s * 4];
                e4.x = ev.x + erv.x; e4.x = e4.x > 0.f ? e4.x : 0.2f * e4.x; e4.x = __expf(e4.x);
                e4.y = ev.y + erv.y; e4.y = e4.y > 0.f ? e4.y : 0.2f * e4.y; e4.y = __expf(e4.y);
                e4.z = ev.z + erv.z; e4.z = e4.z > 0.f ? e4.z : 0.2f * e4.z; e4.z = __expf(e4.z);
                e4.w = ev.w + erv.w; e4.w = e4.w > 0.f ? e4.w : 0.2f * e4.w; e4.w = __expf(e4.w);
            }
            int s0 = __shfl(s, 0);
            if (l >= cnt) s = s0;        // hot line per node, zero weight
            U.g.sS[w][l] = s;
            *(float4*)&U.g.sE[w][l][0] = e4;
            __builtin_amdgcn_wave_barrier();
            // phase B: 16 feat rows in flight per round
            int rounds = (cnt + 15) >> 4;
            for (int r = 0; r < rounds; r++) {
                int e = r * 16;
                int ss[16]; float xx[16]; uint32_t uu[16];
#pragma unroll
                for (int q = 0; q < 16; q++) {
                    ss[q] = U.g.sS[w][e + q];
                    xx[q] = U.g.sE[w][e + q][hh];
                }
#pragma unroll
                for (int q = 0; q < 16; q++)
                    uu[q] = feat[(uint32_t)ss[q] * 64u + (uint32_t)l];
#pragma unroll
                for (int q = 0; q < 16; q++) {
                    den += xx[q];
                    acc.x = fmaf(xx[q], __uint_as_float(uu[q] << 16), acc.x);
                    acc.y = fmaf(xx[q], __uint_as_float(uu[q] & 0xffff0000u), acc.y);
                }
            }
            __builtin_amdgcn_wave_barrier();
        }
        float inv = 1.f / fmaxf(den, 1e-9f);
        float2 val;
        val.x = acc.x * inv + bias_gat[c0];
        val.y = acc.y * inv + bias_gat[c0 + 1];
        __syncthreads();                      // all waves done with U.g before sv aliases it
        *(float2*)&U.e.sv[w][c0] = val;
        __syncthreads();
        // epilogue: out = h + ELU(sv @ Wout + b_out)
        float p = 0.f;
        const float* vv = U.e.sv[w];
#pragma unroll 16
        for (int cc = g2 * 64; cc < g2 * 64 + 64; cc++)
            p = fmaf(vv[cc], sW[cc * 32 + j], p);
        U.e.sacc[w][g2][j] = p;
        __syncthreads();
        if (g2 == 0) {
            float a = U.e.sacc[w][0][j] + U.e.sacc[w][1][j] + b_out[j];
            a = a > 0.f ? a : expm1f(a);
            out[n * 32 + j] = hin[n * 32 + j] + a;
        }
        __syncthreads();                      // epilogue reads done before next group's U.g
    }
}

extern "C" void kernel_launch(void* const* d_in, const int* in_sizes, int n_in,
                              void* d_out, int out_size, void* d_ws, size_t ws_size,
                              hipStream_t stream) {
    const float* hin      = (const float*)d_in[0];
    const int*   src      = (const int*)d_in[1];
    const int*   dst      = (const int*)d_in[2];
    const float* Wfc      = (const float*)d_in[3];
    const float* attn_l   = (const float*)d_in[4];
    const float* attn_r   = (const float*)d_in[5];
    const float* bias_gat = (const float*)d_in[6];
    const float* Wout     = (const float*)d_in[7];
    const float* b_out    = (const float*)d_in[8];
    float* out = (float*)d_out;

    char* ws = (char*)d_ws;
    size_t o = 0;
    uint32_t* feat = (uint32_t*)(ws + o); o += (size_t)NNODE * 64 * 4;  // bf16 x128
    float* el      = (float*)(ws + o);    o += (size_t)NNODE * 4 * 4;
    float* er      = (float*)(ws + o);    o += (size_t)NNODE * 4 * 4;
    int*   cnt     = (int*)(ws + o);      o += (size_t)NNODE * 4;
    unsigned* word = (unsigned*)(ws + o); o += (size_t)NBLK_SCAN * 4;   // contiguous w/ cnt
    int*   offa    = (int*)(ws + o);      o += (size_t)(NNODE + 1) * 4;
    int*   pos     = (int*)(ws + o);      o += (size_t)NEDGE * 4;
    int*   ssrc    = (int*)(ws + o);      o += (size_t)NEDGE * 4;

    // zero cnt + scan words each launch (flags must reset for determinism)
    hipMemsetAsync(cnt, 0, (size_t)(NNODE + NBLK_SCAN) * 4, stream);

    k_proj_hist<<<KPH_BLOCKS, 256, 0, stream>>>(
        hin, Wfc, attn_l, attn_r, feat, el, er, dst, cnt, pos);
    k_scan<<<NBLK_SCAN, 256, 0, stream>>>(cnt, word, offa);
    k_scatter<<<(NEDGE / 4 + 255) / 256, 256, 0, stream>>>(src, dst, pos, offa, ssrc);
    k_gather<<<NNODE / (NPB * NGROUP), 256, 0, stream>>>(offa, ssrc, el, er, feat, bias_gat,
                                                         Wout, b_out, hin, out);
}

// Round 11
// 222.570 us; speedup vs baseline: 1.0354x; 1.0354x over previous
//
#include <hip/hip_runtime.h>
#include <hip/hip_bf16.h>

#define NNODE 100000
#define NEDGE 1600000
#define NBLK_SCAN 98     // ceil(100000/1024)
#define KPH_BLOCKS 1564  // covers 100096 nodes (64/block) and 400384 int4 edges
#define QINT4 100000     // int4s per histogram part (4 parts x 400k edges)
#define FLAGBIT 0x80000000u

static __device__ __forceinline__ uint32_t pack_bf16(float a, float b) {
    __hip_bfloat162 t = __float22bfloat162_rn(make_float2(a, b));
    return *(uint32_t*)&t;
}

// ---------------- K1: 4-way split hist atomics + register-only proj, fused ----------------
__global__ __launch_bounds__(256) void k_proj_hist(
        const float* __restrict__ hin, const float* __restrict__ Wfc,
        const float* __restrict__ attn_l, const float* __restrict__ attn_r,
        uint32_t* __restrict__ feat, float* __restrict__ el, float* __restrict__ er,
        const int* __restrict__ dst, int* __restrict__ cnt, int* __restrict__ pos) {
    int tid = threadIdx.x;
    // ---- hist: one int4 per thread, atomics to this quarter's sub-histogram ----
    int ei = blockIdx.x * 256 + tid;
    bool have = ei < NEDGE / 4;
    int4 d, p;
    int* cntp = nullptr;
    if (have) {
        unsigned part = (unsigned)ei / (unsigned)QINT4;   // 0..3
        cntp = cnt + part * NNODE;
        d = ((const int4*)dst)[ei];
        p.x = atomicAdd(&cntp[d.x], 1);
        p.y = atomicAdd(&cntp[d.y], 1);
        p.z = atomicAdd(&cntp[d.z], 1);
        p.w = atomicAdd(&cntp[d.w], 1);
    }
    // ---- proj: 16 nodes per wave, lane owns 2 cols, W pair in regs ----
    int l = tid & 63;
    int w = tid >> 6;
    int nbase = blockIdx.x * 64 + w * 16;
    int c0 = l * 2;
    float2 wreg[32];
#pragma unroll
    for (int k = 0; k < 32; k++)
        wreg[k] = *(const float2*)&Wfc[k * 128 + c0];
    float al0 = attn_l[c0], al1 = attn_l[c0 + 1];
    float ar0 = attn_r[c0], ar1 = attn_r[c0 + 1];
#pragma unroll 4
    for (int i = 0; i < 16; i++) {
        int n = nbase + i;
        if (n >= NNODE) break;           // wave-uniform
        float4 hv[8];
#pragma unroll
        for (int j = 0; j < 8; j++)
            hv[j] = *(const float4*)&hin[n * 32 + j * 4];   // broadcast load
        float a0 = 0.f, a1 = 0.f;
#pragma unroll
        for (int j = 0; j < 8; j++) {
            a0 = fmaf(hv[j].x, wreg[j * 4 + 0].x, a0); a1 = fmaf(hv[j].x, wreg[j * 4 + 0].y, a1);
            a0 = fmaf(hv[j].y, wreg[j * 4 + 1].x, a0); a1 = fmaf(hv[j].y, wreg[j * 4 + 1].y, a1);
            a0 = fmaf(hv[j].z, wreg[j * 4 + 2].x, a0); a1 = fmaf(hv[j].z, wreg[j * 4 + 2].y, a1);
            a0 = fmaf(hv[j].w, wreg[j * 4 + 3].x, a0); a1 = fmaf(hv[j].w, wreg[j * 4 + 3].y, a1);
        }
        float ep = a0 * al0 + a1 * al1;
        float rp = a0 * ar0 + a1 * ar1;
#pragma unroll
        for (int m = 8; m; m >>= 1) {
            ep += __shfl_xor(ep, m);
            rp += __shfl_xor(rp, m);
        }
        if ((l & 15) == 0) {
            el[n * 4 + (l >> 4)] = ep;
            er[n * 4 + (l >> 4)] = rp;
        }
        feat[(size_t)n * 64 + l] = pack_bf16(a0, a1);       // coalesced u32
    }
    // ---- pos (within-part rank) write: waits on atomic returns (hidden behind proj) ----
    if (have) ((int4*)pos)[ei] = p;
}

// ---------------- single-kernel scan: cnt4 -> offa + per-part bases pb[4][N] ----------------
__global__ __launch_bounds__(256) void k_scan(
        const int* __restrict__ cnt, unsigned* __restrict__ word,
        int* __restrict__ offa, int* __restrict__ pb) {
    __shared__ int s[256];
    __shared__ int sBase;
    int t = threadIdx.x;
    int b = blockIdx.x;
    int base = b * 1024 + t * 4;
    int vA[4], vB[4], vC[4], v[4];
#pragma unroll
    for (int i = 0; i < 4; i++) {
        int n = base + i;
        if (n < NNODE) {
            int a = cnt[n], bb = cnt[NNODE + n], c = cnt[2 * NNODE + n], dd = cnt[3 * NNODE + n];
            vA[i] = a; vB[i] = bb; vC[i] = c;
            v[i] = a + bb + c + dd;
        } else { vA[i] = vB[i] = vC[i] = 0; v[i] = 0; }
    }
    int sum = v[0] + v[1] + v[2] + v[3];
    s[t] = sum;
    __syncthreads();
    for (int d = 1; d < 256; d <<= 1) {
        int x = (t >= d) ? s[t - d] : 0;
        __syncthreads();
        s[t] += x;
        __syncthreads();
    }
    int excl = s[t] - sum;
    if (t == 255)
        __hip_atomic_store(&word[b], (unsigned)s[255] | FLAGBIT,
                           __ATOMIC_RELEASE, __HIP_MEMORY_SCOPE_AGENT);
    if (t < 64) {
        unsigned acc = 0;
        for (int i = t; i < b; i += 64) {
            unsigned wv;
            do {
                wv = __hip_atomic_load(&word[i], __ATOMIC_ACQUIRE, __HIP_MEMORY_SCOPE_AGENT);
            } while (!(wv & FLAGBIT));
            acc += wv & ~FLAGBIT;
        }
#pragma unroll
        for (int o = 32; o; o >>= 1) acc += __shfl_down(acc, o);
        if (t == 0) sBase = (int)acc;
    }
    __syncthreads();
    int o0 = sBase + excl;
#pragma unroll
    for (int i = 0; i < 4; i++) {
        int n = base + i;
        if (n < NNODE) {
            offa[n] = o0;
            pb[n] = o0;
            pb[NNODE + n] = o0 + vA[i];
            pb[2 * NNODE + n] = o0 + vA[i] + vB[i];
            pb[3 * NNODE + n] = o0 + vA[i] + vB[i] + vC[i];
            o0 += v[i];
        }
    }
    if (b == NBLK_SCAN - 1 && t == 255) offa[NNODE] = NEDGE;
}

// ---------------- scatter: atomic-free, part-base + within-part rank ----------------
__global__ __launch_bounds__(256) void k_scatter(const int* __restrict__ src,
                                                 const int* __restrict__ dst,
                                                 const int* __restrict__ pos,
                                                 const int* __restrict__ pb,
                                                 int* __restrict__ ssrc) {
    int i = blockIdx.x * 256 + threadIdx.x;
    if (i >= NEDGE / 4) return;
    unsigned part = (unsigned)i / (unsigned)QINT4;
    const int* pbp = pb + part * NNODE;
    int4 s = ((const int4*)src)[i];
    int4 d = ((const int4*)dst)[i];
    int4 p = ((const int4*)pos)[i];
    int o0 = pbp[d.x];
    int o1 = pbp[d.y];
    int o2 = pbp[d.z];
    int o3 = pbp[d.w];
    ssrc[o0 + p.x] = s.x;
    ssrc[o1 + p.y] = s.y;
    ssrc[o2 + p.z] = s.z;
    ssrc[o3 + p.w] = s.w;
}

// ---------------- K2': wave-per-node gather (R9 structure) + bf16 Wout in LDS ----
#define NPB 4
union SmemU {
    struct { int sS[NPB][64]; float sE[NPB][64][4]; } g;      // gather phase
    struct { float sv[NPB][128]; float sacc[NPB][2][32]; } e; // epilogue phase
};

__global__ __launch_bounds__(256) void k_gather(
        const int* __restrict__ off, const int* __restrict__ ssrc,
        const float* __restrict__ el, const float* __restrict__ er,
        const uint32_t* __restrict__ feat, const float* __restrict__ bias_gat,
        const float* __restrict__ Wout, const float* __restrict__ b_out,
        const float* __restrict__ hin, float* __restrict__ out) {
    __shared__ uint32_t sWu[64 * 32];           // 8 KB: bf16 pair (cols 2cc,2cc+1) per word
    __shared__ __align__(16) SmemU U;           // 5 KB
    int tid = threadIdx.x;
    for (int i = tid; i < 2048; i += 256) {
        int ccp = i >> 5, j = i & 31;
        sWu[i] = pack_bf16(Wout[(2 * ccp) * 32 + j], Wout[(2 * ccp + 1) * 32 + j]);
    }
    int w = tid >> 6;
    int l = tid & 63;
    int n = blockIdx.x * NPB + w;   // grid exact: 25000*4 = 100000
    int c0 = l * 2;
    int hh = l >> 4;
    float2 acc = make_float2(0.f, 0.f);
    float den = 0.f;
    int beg = off[n], end = off[n + 1];
    float4 erv = *(const float4*)&er[n * 4];

    for (int base = beg; base < end; base += 64) {
        int cnt = end - base; if (cnt > 64) cnt = 64;
        // phase A: pad to 8-multiple with zero weights (s=0 row is valid memory)
        int s = 0;
        float4 e4 = make_float4(0.f, 0.f, 0.f, 0.f);
        if (l < cnt) {
            s = ssrc[base + l];
            float4 ev = *(const float4*)&el[s * 4];
            e4.x = ev.x + erv.x; e4.x = e4.x > 0.f ? e4.x : 0.2f * e4.x; e4.x = __expf(e4.x);
            e4.y = ev.y + erv.y; e4.y = e4.y > 0.f ? e4.y : 0.2f * e4.y; e4.y = __expf(e4.y);
            e4.z = ev.z + erv.z; e4.z = e4.z > 0.f ? e4.z : 0.2f * e4.z; e4.z = __expf(e4.z);
            e4.w = ev.w + erv.w; e4.w = e4.w > 0.f ? e4.w : 0.2f * e4.w; e4.w = __expf(e4.w);
        }
        U.g.sS[w][l] = s;
        *(float4*)&U.g.sE[w][l][0] = e4;
        __builtin_amdgcn_wave_barrier();
        // phase B: unconditional 8-deep groups (padding contributes exactly 0)
        int rounds = (cnt + 7) >> 3;
        for (int r = 0; r < rounds; r++) {
            int e = r * 8;
            int ss[8]; float xx[8]; uint32_t uu[8];
#pragma unroll
            for (int q = 0; q < 8; q++) {
                ss[q] = U.g.sS[w][e + q];
                xx[q] = U.g.sE[w][e + q][hh];
            }
#pragma unroll
            for (int q = 0; q < 8; q++)
                uu[q] = feat[(uint32_t)ss[q] * 64u + (uint32_t)l];
#pragma unroll
            for (int q = 0; q < 8; q++) {
                den += xx[q];
                acc.x = fmaf(xx[q], __uint_as_float(uu[q] << 16), acc.x);
                acc.y = fmaf(xx[q], __uint_as_float(uu[q] & 0xffff0000u), acc.y);
            }
        }
        __builtin_amdgcn_wave_barrier();
    }
    float inv = 1.f / fmaxf(den, 1e-9f);
    float2 val;
    val.x = acc.x * inv + bias_gat[c0];
    val.y = acc.y * inv + bias_gat[c0 + 1];
    __syncthreads();                      // all waves done with U.g before sv aliases it
    *(float2*)&U.e.sv[w][c0] = val;
    __syncthreads();
    // epilogue: out = h + ELU(sv @ Wout + b_out); Wout from packed bf16 LDS
    int j = tid & 31, g2 = (l >> 5);
    float p = 0.f;
    const float* vv = U.e.sv[w];
#pragma unroll 8
    for (int ccp = g2 * 32; ccp < g2 * 32 + 32; ccp++) {
        uint32_t u = sWu[ccp * 32 + j];
        p = fmaf(vv[2 * ccp],     __uint_as_float(u << 16),          p);
        p = fmaf(vv[2 * ccp + 1], __uint_as_float(u & 0xffff0000u), p);
    }
    U.e.sacc[w][g2][j] = p;
    __syncthreads();
    if (g2 == 0) {
        float a = U.e.sacc[w][0][j] + U.e.sacc[w][1][j] + b_out[j];
        a = a > 0.f ? a : expm1f(a);
        out[n * 32 + j] = hin[n * 32 + j] + a;
    }
}

extern "C" void kernel_launch(void* const* d_in, const int* in_sizes, int n_in,
                              void* d_out, int out_size, void* d_ws, size_t ws_size,
                              hipStream_t stream) {
    const float* hin      = (const float*)d_in[0];
    const int*   src      = (const int*)d_in[1];
    const int*   dst      = (const int*)d_in[2];
    const float* Wfc      = (const float*)d_in[3];
    const float* attn_l   = (const float*)d_in[4];
    const float* attn_r   = (const float*)d_in[5];
    const float* bias_gat = (const float*)d_in[6];
    const float* Wout     = (const float*)d_in[7];
    const float* b_out    = (const float*)d_in[8];
    float* out = (float*)d_out;

    char* ws = (char*)d_ws;
    size_t o = 0;
    uint32_t* feat = (uint32_t*)(ws + o); o += (size_t)NNODE * 64 * 4;  // bf16 x128
    float* el      = (float*)(ws + o);    o += (size_t)NNODE * 4 * 4;
    float* er      = (float*)(ws + o);    o += (size_t)NNODE * 4 * 4;
    int*   cnt     = (int*)(ws + o);      o += (size_t)4 * NNODE * 4;   // 4 sub-histograms
    unsigned* word = (unsigned*)(ws + o); o += (size_t)NBLK_SCAN * 4;   // contiguous w/ cnt
    int*   offa    = (int*)(ws + o);      o += (size_t)(NNODE + 1) * 4;
    int*   pb      = (int*)(ws + o);      o += (size_t)4 * NNODE * 4;   // per-part bases
    int*   pos     = (int*)(ws + o);      o += (size_t)NEDGE * 4;
    int*   ssrc    = (int*)(ws + o);      o += (size_t)NEDGE * 4;

    // zero cnt4 + scan words each launch (flags must reset for determinism)
    hipMemsetAsync(cnt, 0, (size_t)(4 * NNODE + NBLK_SCAN) * 4, stream);

    k_proj_hist<<<KPH_BLOCKS, 256, 0, stream>>>(
        hin, Wfc, attn_l, attn_r, feat, el, er, dst, cnt, pos);
    k_scan<<<NBLK_SCAN, 256, 0, stream>>>(cnt, word, offa, pb);
    k_scatter<<<(NEDGE / 4 + 255) / 256, 256, 0, stream>>>(src, dst, pos, pb, ssrc);
    k_gather<<<NNODE / NPB, 256, 0, stream>>>(offa, ssrc, el, er, feat, bias_gat,
                                              Wout, b_out, hin, out);
}